// Round 16
// baseline (394.955 us; speedup 1.0000x reference)
//
#include <hip/hip_runtime.h>
#include <hip/hip_bf16.h>
#include <stdint.h>

#define P    300
#define HID  128
#define NG   1000
#define QR   80          // quarter rows: 79 valid (75 owned + 2+2 halo) + 1 pad

typedef __attribute__((ext_vector_type(8))) short bf16x8;
typedef __attribute__((ext_vector_type(4))) float f32x4;

// Swizzled bf16 W^T. Slot fkey holds weights for column perm(fkey):
// W2 (pass0): perm(fkey) = u*32 + 2*(fkey&15) + ((fkey>>4)&1), u=fkey>>5
//   -> computed feature IS the physical store position, so h2 is natural
//      and W3 (pass1) is natural. chunk(fkey,kc) at fkey*16+(kc^(fkey&15)).
__device__ short g_wsw[2 * HID * HID];
__device__ float g_pool[NG * 4 * HID];   // [graph][quarter][feature] partials
__device__ int   g_cnt[NG];              // completion counters (self-resetting)

__device__ __forceinline__ short f2bf(float f) {
    union { float f; uint32_t u; } v; v.f = f;
    uint32_t r = v.u + 0x7fffu + ((v.u >> 16) & 1u);   // RNE
    return (short)(r >> 16);
}
__device__ __forceinline__ float bf2f(short s) {
    union { uint32_t u; float f; } v; v.u = ((uint32_t)(uint16_t)s) << 16;
    return v.f;
}
__device__ __forceinline__ uint32_t pkbf2(float a, float b) {   // low=a, high=b
    union { __hip_bfloat162 h; uint32_t u; } cv;
    cv.h = __float22bfloat162_rn(float2{a, b});
    return cv.u;
}
__device__ __forceinline__ float unpk(int v, int ft) {
    return bf2f((short)(ft ? (((uint32_t)v) >> 16) : (v & 0xffff)));
}

__global__ __launch_bounds__(256) void k_prep(const float* __restrict__ W2,
                                              const float* __restrict__ W3) {
    int b = blockIdx.x;                       // 16 blocks
    const bool perm = (b < 8);
    const float* W = perm ? W2 : W3;
    short* dst = g_wsw + (perm ? 0 : HID * HID);
    int t    = (b & 7) * 256 + threadIdx.x;   // 0..2047 chunks
    int fkey = t >> 4;
    int kc   = t & 15;
    int fsrc;
    if (perm) {
        int u = fkey >> 5, ft = (fkey >> 4) & 1, l = fkey & 15;
        fsrc = u * 32 + 2 * l + ft;
    } else fsrc = fkey;
    bf16x8 o;
    #pragma unroll
    for (int j = 0; j < 8; ++j)
        o[j] = f2bf(W[(kc * 8 + j) * HID + fsrc]);
    *(bf16x8*)&dst[(fkey * 16 + (kc ^ (fkey & 15))) * 8] = o;
}

// ring-average + bias + relu over 4 consecutive node-rows (f32 in regs)
__device__ __forceinline__ void avg_epi(const f32x4 &G, float vp0, float vn3,
                                        float b, float* o) {
    o[0] = (vp0  + G[0] + G[1]) * (1.0f / 3.0f) + b;
    o[1] = (G[0] + G[1] + G[2]) * (1.0f / 3.0f) + b;
    o[2] = (G[1] + G[2] + G[3]) * (1.0f / 3.0f) + b;
    o[3] = (G[2] + G[3] + vn3 ) * (1.0f / 3.0f) + b;
    #pragma unroll
    for (int i = 0; i < 4; ++i) o[i] = o[i] > 0.f ? o[i] : 0.f;
}

// One GCN layer over a QUARTER-ring (path, 5 tiles, 80 rows); 4 waves,
// 2 ft-tiles/wave. Identical to r15 (best kernel time, 48.8 us).
// ROLLING 2-BARRIER path schedule, race-proof:
//   reads {0,1,2}; BAR1; reads {3,4} interleaved w/ stores {0,1}; BAR2;
//   stores {2,3,4}. Stores{0,1} vs reads{3,4}: disjoint; all reads of a
//   tile precede its store via the preceding barrier.
// Row masks [LO,HI] compile-time: pass0 [1,77], pass1 [2,76] (=owned).
template<int POOL, int LO, int HI>
__device__ __forceinline__ void run_pass(short* __restrict__ buf,
                                         const short* __restrict__ wbase,
                                         const float* __restrict__ bias,
                                         float* __restrict__ pool, int tid) {
    const int lane = tid & 63, wv = tid >> 6, q = lane >> 4, lm = lane & 15;
    const int ftg0 = wv * 2;
    bf16x8 wf[2][4];
    #pragma unroll
    for (int ft = 0; ft < 2; ++ft) {
        int fkey = (ftg0 + ft) * 16 + lm;
        #pragma unroll
        for (int kk = 0; kk < 4; ++kk)
            wf[ft][kk] = *(const bf16x8*)&wbase[(fkey * 16 + ((4 * kk + q) ^ lm)) * 8];
    }
    float biaf[2];
    #pragma unroll
    for (int ft = 0; ft < 2; ++ft)
        biaf[ft] = POOL ? bias[(ftg0 + ft) * 16 + lm] : bias[wv * 32 + 2 * lm + ft];
    const int fpair = wv * 32 + 2 * lm;       // even physical feature (pass0)
    const int kcs = fpair >> 3, offs = fpair & 7;
    const int sA = (q == 0) ? (48 + lm) : (lane - 16);  // r15 carry / row above
    const int sB = (lane + 16) & 63;                    // row below (q<3)

    float psum[2] = {0.f, 0.f};
    float c15[2] = {0.f, 0.f};

    auto mfma_tile = [&](int t, f32x4 (&G)[2]) {
        const short* tb = buf + t * 2048;
        G[0] = f32x4{0.f, 0.f, 0.f, 0.f};
        G[1] = f32x4{0.f, 0.f, 0.f, 0.f};
        #pragma unroll
        for (int kk = 0; kk < 4; ++kk) {
            bf16x8 af = *(const bf16x8*)&tb[(lm * 16 + ((4 * kk + q) ^ lm)) * 8];
            G[0] = __builtin_amdgcn_mfma_f32_16x16x32_bf16(af, wf[0][kk], G[0], 0, 0, 0);
            G[1] = __builtin_amdgcn_mfma_f32_16x16x32_bf16(af, wf[1][kk], G[1], 0, 0, 0);
        }
    };
    auto store_rows = [&](int T, float (&o)[2][4]) {
        #pragma unroll
        for (int i = 0; i < 4; ++i) {
            int r = T * 16 + q * 4 + i;
            if (r >= LO && r <= HI)
                *(uint32_t*)&buf[(r * 16 + (kcs ^ (r & 15))) * 8 + offs] =
                    pkbf2(o[0][i], o[1][i]);
        }
    };
    auto accum = [&](int T, float (&o)[2][4]) {
        #pragma unroll
        for (int i = 0; i < 4; ++i) {
            int r = T * 16 + q * 4 + i;
            if (r >= LO && r <= HI) { psum[0] += o[0][i]; psum[1] += o[1][i]; }
        }
    };
    // packed epilogue (r4-proven): E centers; N = next tile (r0 only used
    // at q==3; garbage OK when those rows are masked).
    auto epi = [&](const f32x4 (&E)[2], const f32x4 (&N)[2], float (&o)[2][4]) {
        uint32_t uE3 = pkbf2(E[0][3], E[1][3]);
        uint32_t uE0 = pkbf2(E[0][0], E[1][0]);
        uint32_t uN0 = pkbf2(N[0][0], N[1][0]);
        int vA = __shfl((int)uE3, sA, 64);
        int vB = __shfl((int)uE0, sB, 64);
        int vC = __shfl((int)uN0, lm, 64);
        #pragma unroll
        for (int ft = 0; ft < 2; ++ft) {
            float bpA = unpk(vA, ft);
            float vp0 = (q == 0) ? c15[ft] : bpA;
            float vn3 = (q == 3) ? unpk(vC, ft) : unpk(vB, ft);
            avg_epi(E[ft], vp0, vn3, biaf[ft], o[ft]);
            c15[ft] = bpA;        // this tile's r15 -> next tile's vp0(q==0)
        }
    };

    f32x4 Ga[2], Gb[2], Gc[2], Gd[2], Ge[2];

    mfma_tile(0, Ga);
    mfma_tile(1, Gb);
    mfma_tile(2, Gc);
    if (!POOL) __syncthreads();               // BAR1: reads {0,1,2} done

    mfma_tile(3, Gd);
    {   // tile 0 (row0's vp0 = c15 garbage -> row0 < LO, masked)
        float o[2][4];
        epi(Ga, Gb, o);
        if (POOL) accum(0, o); else store_rows(0, o);
    }
    mfma_tile(4, Ge);
    {   // tile 1
        float o[2][4];
        epi(Gb, Gc, o);
        if (POOL) accum(1, o); else store_rows(1, o);
    }
    if (!POOL) __syncthreads();               // BAR2: reads {3,4} done

    {
        float o[2][4];
        epi(Gc, Gd, o);
        if (POOL) accum(2, o); else store_rows(2, o);
    }
    {
        float o[2][4];
        epi(Gd, Ge, o);
        if (POOL) accum(3, o); else store_rows(3, o);
    }
    {   // tile 4: N unused for valid rows (rows 78,79 masked)
        float o[2][4];
        epi(Ge, Ge, o);
        if (POOL) accum(4, o); else store_rows(4, o);
    }

    if (POOL) {
        #pragma unroll
        for (int ft = 0; ft < 2; ++ft) {
            psum[ft] += __shfl_xor(psum[ft], 16, 64);
            psum[ft] += __shfl_xor(psum[ft], 32, 64);
        }
        if (q == 0) {
            pool[ftg0 * 16 + lm]        = psum[0];
            pool[(ftg0 + 1) * 16 + lm]  = psum[1];
        }
    }
}

// One block (256 thr, 4 waves) per QUARTER-graph; the LAST finisher of
// each graph's 4 quarters also runs the FC head (completion-counter
// pattern: threadfence + device-scope atomics; no dispatch-order
// assumption -- Guideline 12/16). Saves the k_fc launch (~8 us measured
// r13->r15 overhead delta). Foreign g_pool partials are read via
// atomicAdd(p, 0.0f) (cache-bypassing) to be safe against per-XCD L2
// staleness. g_cnt self-resets (last block stores 0) so graph-replay
// iterations see a clean counter; kernel boundary orders runs.
__global__ __launch_bounds__(256, 2) void k_graph(
        const float* __restrict__ x,
        const float* __restrict__ W1,  const float* __restrict__ b1,
        const float* __restrict__ b2v, const float* __restrict__ b3v,
        const float* __restrict__ fw1, const float* __restrict__ fb1,
        const float* __restrict__ fw2, const float* __restrict__ fb2,
        float* __restrict__ out) {
    __shared__ __align__(16) short buf[QR * HID];   // 20480 B, chunk-swizzled
    __shared__ __align__(16) float xs[164];         // 656 B
    __shared__ float pl[128], s1f[128];
    __shared__ int is_last;
    const int bid = blockIdx.x, g = bid >> 2, qt = bid & 3;
    const int tid = threadIdx.x;
    const int start = qt * 75;

    // stage x for nodes (start-3 .. start+77) mod 300: xs[2t] <-> start-3+t
    if (tid < 81) {
        int gn = start - 3 + tid;
        gn += (gn < 0) ? P : 0;
        gn -= (gn >= P) ? P : 0;
        *(float2*)&xs[2 * tid] = *(const float2*)&x[g * 600 + gn * 2];
    }
    __syncthreads();

    // ---- layer 1: h1[lr] = relu(avg3(x)@W1+b1), lr 0..78; row 79 zero ----
    {
        const int kc1 = tid & 15;
        const int n0  = tid >> 4;            // 0..15
        float w1x[8], w1y[8], b1v[8];
        #pragma unroll
        for (int j = 0; j < 8; ++j) {
            w1x[j] = W1[kc1 * 8 + j];
            w1y[j] = W1[HID + kc1 * 8 + j];
            b1v[j] = b1[kc1 * 8 + j];
        }
        #pragma unroll
        for (int it = 0; it < 5; ++it) {
            int row = it * 16 + n0;          // 0..79
            uint32_t w[4] = {0u, 0u, 0u, 0u};
            if (row < 79) {
                float2 xp = *(const float2*)&xs[2 * row];
                float2 xc = *(const float2*)&xs[2 * row + 2];
                float2 xn = *(const float2*)&xs[2 * row + 4];
                float ax = (xp.x + xc.x + xn.x) * (1.f / 3.f);
                float ay = (xp.y + xc.y + xn.y) * (1.f / 3.f);
                #pragma unroll
                for (int jj = 0; jj < 4; ++jj) {
                    float va = ax * w1x[2*jj]   + ay * w1y[2*jj]   + b1v[2*jj];
                    float vb = ax * w1x[2*jj+1] + ay * w1y[2*jj+1] + b1v[2*jj+1];
                    va = va > 0.f ? va : 0.f;
                    vb = vb > 0.f ? vb : 0.f;
                    w[jj] = pkbf2(va, vb);
                }
            }
            *(uint4*)&buf[(row * 16 + (kc1 ^ (row & 15))) * 8] =
                uint4{w[0], w[1], w[2], w[3]};
        }
    }
    __syncthreads();

    run_pass<0, 1, 77>(buf, g_wsw,             b2v, nullptr, tid);
    __syncthreads();
    run_pass<1, 2, 76>(buf, g_wsw + HID * HID, b3v,
                       &g_pool[(g * 4 + qt) * HID], tid);

    // ---- completion counter; last quarter runs the FC head ----
    __syncthreads();                          // pool writes done block-wide
    __threadfence();                          // release g_pool to device
    if (tid == 0) is_last = (atomicAdd(&g_cnt[g], 1) == 3);
    __syncthreads();
    if (!is_last) return;

    if (tid < 128) {                          // gather 4 partials (atomic loads)
        float v = 0.f;
        #pragma unroll
        for (int qq = 0; qq < 4; ++qq)
            v += atomicAdd(&g_pool[(g * 4 + qq) * HID + tid], 0.0f);
        pl[tid] = v;
    }
    __syncthreads();
    if (tid < 128) {
        float p = 0.f;
        const float* c = fw1 + tid;
        #pragma unroll 8
        for (int k = 0; k < 128; ++k) p += pl[k] * c[k * 128];
        float o1 = fb1[tid] + p * (1.0f / 300.0f);
        s1f[tid] = o1 > 0.f ? o1 : 0.f;
    }
    __syncthreads();
    if (tid < 128) {
        int o = tid >> 6, ln = tid & 63;
        float v = s1f[ln] * fw2[ln * 2 + o] + s1f[ln + 64] * fw2[(ln + 64) * 2 + o];
        #pragma unroll
        for (int off = 1; off <= 32; off <<= 1)
            v += __shfl_xor(v, off, 64);
        if (ln == 0) out[g * 2 + o] = v + fb2[o];
    }
    if (tid == 0) atomicExch(&g_cnt[g], 0);   // reset for next run
}

extern "C" void kernel_launch(void* const* d_in, const int* in_sizes, int n_in,
                              void* d_out, int out_size, void* d_ws, size_t ws_size,
                              hipStream_t stream) {
    const float* x   = (const float*)d_in[0];
    const float* W1  = (const float*)d_in[3];
    const float* b1  = (const float*)d_in[4];
    const float* W2  = (const float*)d_in[5];
    const float* b2  = (const float*)d_in[6];
    const float* W3  = (const float*)d_in[7];
    const float* b3  = (const float*)d_in[8];
    const float* fw1 = (const float*)d_in[9];
    const float* fb1 = (const float*)d_in[10];
    const float* fw2 = (const float*)d_in[11];
    const float* fb2 = (const float*)d_in[12];
    float* out = (float*)d_out;

    k_prep <<<dim3(16),     dim3(256), 0, stream>>>(W2, W3);
    k_graph<<<dim3(4 * NG), dim3(256), 0, stream>>>(x, W1, b1, b2, b3,
                                                    fw1, fb1, fw2, fb2, out);
}

// Round 17
// 121.706 us; speedup vs baseline: 3.2452x; 3.2452x over previous
//
#include <hip/hip_runtime.h>
#include <hip/hip_bf16.h>
#include <stdint.h>

#define P    300
#define HID  128
#define NG   1000
#define NTL  19          // 16-node tiles (304 rows, 300 valid)

typedef __attribute__((ext_vector_type(8))) short bf16x8;
typedef __attribute__((ext_vector_type(4))) float f32x4;

// Swizzled bf16 W^T, NATURAL feature order both layers (1-ft/wave needs
// no store-pairing permutation). chunk(fkey,kc) at fkey*16+(kc^(fkey&15)).
__device__ short g_wsw[2 * HID * HID];

__device__ __forceinline__ short f2bf(float f) {
    union { float f; uint32_t u; } v; v.f = f;
    uint32_t r = v.u + 0x7fffu + ((v.u >> 16) & 1u);   // RNE
    return (short)(r >> 16);
}
__device__ __forceinline__ uint32_t pkbf2(float a, float b) {   // low=a, high=b
    union { __hip_bfloat162 h; uint32_t u; } cv;
    cv.h = __float22bfloat162_rn(float2{a, b});
    return cv.u;
}

__global__ __launch_bounds__(256) void k_prep(const float* __restrict__ W2,
                                              const float* __restrict__ W3) {
    int b = blockIdx.x;                       // 16 blocks
    const float* W = (b < 8) ? W2 : W3;
    short* dst = g_wsw + ((b < 8) ? 0 : HID * HID);
    int t    = (b & 7) * 256 + threadIdx.x;   // 0..2047 chunks
    int fkey = t >> 4;
    int kc   = t & 15;
    bf16x8 o;
    #pragma unroll
    for (int j = 0; j < 8; ++j)
        o[j] = f2bf(W[(kc * 8 + j) * HID + fkey]);
    *(bf16x8*)&dst[(fkey * 16 + (kc ^ (fkey & 15))) * 8] = o;
}

// ring-average + bias + relu over 4 consecutive node-rows (f32 in regs)
__device__ __forceinline__ void avg_epi(const f32x4 &G, float vp0, float vn3,
                                        float b, float* o) {
    o[0] = (vp0  + G[0] + G[1]) * (1.0f / 3.0f) + b;
    o[1] = (G[0] + G[1] + G[2]) * (1.0f / 3.0f) + b;
    o[2] = (G[1] + G[2] + G[3]) * (1.0f / 3.0f) + b;
    o[3] = (G[2] + G[3] + vn3 ) * (1.0f / 3.0f) + b;
    #pragma unroll
    for (int i = 0; i < 4; ++i) o[i] = o[i] > 0.f ? o[i] : 0.f;
}

// One GCN layer; 8 waves, wave wv owns ft-tile wv (1 ft-tile = 16
// features; fkey = wv*16+lm). Feature-split = zero duplicated MFMAs.
// This is the measured session-best configuration (r13: bench 121.56 us,
// k_graph 51 us). r16's completion-counter FC fusion regressed 6.8x
// (device-scope fence+atomic stalls resident waves); full-graph blocks
// with the FC in-block need no cross-block communication at all.
// 3-PHASE / 2-BARRIER schedule (r4-proven race-free):
//   A: MFMA tiles {10..18, 0} -> GH (reads only); barrier
//   B: i=0..8: MFMA tile 9-i -> GL[i]; epi/store tiles 10..18, 0
//      (reads {9..1} vs stores {10..18,0}: DISJOINT); barrier
//   C: epi/store tiles 1..9 (stores only)
// Epilogue: RAW-F32 shuffles (no pack/unpack -- 1 ft/wave ships one
// float per shuffle): vA = row above / r15-carry, vB = row below,
// vC = next-tile r0. Wraps: tile0.vp0(q0) = G18 r11 (lane 32+lm),
// tile18.vn3(q2) = G0 r0, tile0.vn3(q3) = G1 r0.
template<int POOL>
__device__ __forceinline__ void run_pass(short* __restrict__ buf,
                                         const short* __restrict__ wbase,
                                         const float* __restrict__ bias,
                                         float* __restrict__ pool, int tid) {
    const int lane = tid & 63, wv = tid >> 6, q = lane >> 4, lm = lane & 15;
    const int fkey = wv * 16 + lm;            // this lane's feature
    bf16x8 wf[4];
    #pragma unroll
    for (int kk = 0; kk < 4; ++kk)
        wf[kk] = *(const bf16x8*)&wbase[(fkey * 16 + ((4 * kk + q) ^ lm)) * 8];
    const float biaf = bias[fkey];
    const int kcs = fkey >> 3, offs = fkey & 7;
    const int sA = (q == 0) ? (48 + lm) : (lane - 16);  // r15 carry / row above
    const int sB = (lane + 16) & 63;                    // row below (q<3)

    float psum = 0.f;

    auto mfma_tile = [&](int t, f32x4 &G) {
        const short* tb = buf + t * 2048;
        G = f32x4{0.f, 0.f, 0.f, 0.f};
        #pragma unroll
        for (int kk = 0; kk < 4; ++kk) {
            bf16x8 af = *(const bf16x8*)&tb[(lm * 16 + ((4 * kk + q) ^ lm)) * 8];
            G = __builtin_amdgcn_mfma_f32_16x16x32_bf16(af, wf[kk], G, 0, 0, 0);
        }
    };
    auto store_rows = [&](int T, float (&o)[4]) {
        uint32_t u01 = pkbf2(o[0], o[1]);
        uint32_t u23 = pkbf2(o[2], o[3]);
        int n0 = T * 16 + q * 4;
        buf[(n0 * 16       + (kcs ^ ( n0      & 15))) * 8 + offs] = (short)u01;
        buf[((n0 + 1) * 16 + (kcs ^ ((n0 + 1) & 15))) * 8 + offs] = (short)(u01 >> 16);
        buf[((n0 + 2) * 16 + (kcs ^ ((n0 + 2) & 15))) * 8 + offs] = (short)u23;
        buf[((n0 + 3) * 16 + (kcs ^ ((n0 + 3) & 15))) * 8 + offs] = (short)(u23 >> 16);
    };
    auto accum = [&](float (&o)[4]) { psum += o[0] + o[1] + o[2] + o[3]; };

    float c15;
    // mid-ring epilogue of tile with centers E; N0 = next tile's G[0]
    auto epi_mid = [&](const f32x4 &E, float N0, float (&o)[4]) {
        float vA = __shfl(E[3], sA, 64);
        float vB = __shfl(E[0], sB, 64);
        float vC = __shfl(N0, lm, 64);
        float vp0 = (q == 0) ? c15 : vA;
        float vn3 = (q == 3) ? vC : vB;
        avg_epi(E, vp0, vn3, biaf, o);
        c15 = vA;                 // this tile's r15 -> next tile's vp0(q==0)
    };

    f32x4 GH[10];   // GH[k] = G[10+k] for k<9; GH[9] = G[0]
    f32x4 GL[9];    // GL[i] = G[9-i]

    // ---- phase A: MFMA tiles 10..18 and 0 (reads only) ----
    #pragma unroll
    for (int k = 0; k < 9; ++k) mfma_tile(10 + k, GH[k]);
    mfma_tile(0, GH[9]);
    if (!POOL) __syncthreads();

    // ---- phase B: MFMA 9..1 interleaved with epi/store of 10..18, 0 ----
    #pragma unroll
    for (int i = 0; i < 9; ++i) {
        mfma_tile(9 - i, GL[i]);
        if (i == 0) c15 = __shfl(GL[0][3], 48 + lm, 64);   // G9 r15 (node 159)
        if (i < 8) {
            float o[4];
            epi_mid(GH[i], GH[i + 1][0], o);
            if (POOL) accum(o); else store_rows(10 + i, o);
        } else {
            // tile 18 (rows 288..299 valid; row299.next = node0)
            float o18[4];
            {
                float vA = __shfl(GH[8][3], sA, 64);
                float vB = __shfl(GH[8][0], sB, 64);
                float vZ = __shfl(GH[9][0], lm, 64);       // G0 r0 (node 0)
                float vp0 = (q == 0) ? c15 : vA;
                float vn3 = (q == 2) ? vZ : vB;
                avg_epi(GH[8], vp0, vn3, biaf, o18);
            }
            if (q < 3) { if (POOL) accum(o18); else store_rows(18, o18); }
            // tile 0 (row0.prev = node299 = G18 r11; row15.next = G1 r0)
            float o0[4];
            {
                float vA0 = __shfl(GH[9][3], (lane - 16) & 63, 64);
                float vB0 = __shfl(GH[9][0], sB, 64);
                float vP  = __shfl(GH[8][3], 32 + lm, 64); // G18 r11 (node 299)
                float vN  = __shfl(GL[8][0], lm, 64);      // G1 r0 (node 16)
                float vp0 = (q == 0) ? vP : vA0;
                float vn3 = (q == 3) ? vN : vB0;
                avg_epi(GH[9], vp0, vn3, biaf, o0);
            }
            if (POOL) accum(o0); else store_rows(0, o0);
        }
    }
    if (!POOL) __syncthreads();

    // ---- phase C: epi/store tiles 1..9 (stores only) ----
    c15 = __shfl(GH[9][3], 48 + lm, 64);                   // G0 r15 (node 15)
    #pragma unroll
    for (int T = 1; T <= 9; ++T) {
        float o[4];
        float N0 = (T < 9) ? GL[8 - T][0] : GH[0][0];      // next tile's r0
        epi_mid(GL[9 - T], N0, o);
        if (POOL) accum(o); else store_rows(T, o);
    }

    if (POOL) {
        psum += __shfl_xor(psum, 16, 64);
        psum += __shfl_xor(psum, 32, 64);
        if (q == 0) pool[fkey] = psum;
    }
}

// One block (512 thr, 8 waves) per graph, feature-split. LDS 80384 B
// (HW-proven 2/CU) -> 16 waves/CU = 4 waves/SIMD. Register gate (r9/r10
// evidence): 2 blocks/CU needs COMBINED VGPR+AGPR <= 128/wave. Live set:
// GH+GL 76 + wf 16 + temps ~25 = ~117. (512,2) caps arch at 128.
__global__ __launch_bounds__(512, 2) void k_graph(
        const float* __restrict__ x,
        const float* __restrict__ W1,  const float* __restrict__ b1,
        const float* __restrict__ b2v, const float* __restrict__ b3v,
        const float* __restrict__ fw1, const float* __restrict__ fb1,
        const float* __restrict__ fw2, const float* __restrict__ fb2,
        float* __restrict__ out) {
    __shared__ __align__(16) short buf[304 * HID];   // 77824 B, chunk-swizzled
    __shared__ __align__(16) float scr[640];         // 2560 B -> total 80384
    float* xs    = scr;          // 600 (layer-1 only, dead after)
    float* pool  = scr;          // 128
    float* parts = scr + 128;    // 256
    float* s1    = scr + 384;    // 128

    const int g = blockIdx.x, tid = threadIdx.x;

    if (tid < 150) *(float4*)&xs[tid * 4] = *(const float4*)&x[g * 600 + tid * 4];
    __syncthreads();

    // ---- layer 1: buf <- relu(avg3(x) @ W1 + b1); rows 300..303 zeroed ----
    {
        const int kc1 = tid & 15;
        const int n0  = tid >> 4;            // 0..31
        float w1x[8], w1y[8], b1v[8];
        #pragma unroll
        for (int j = 0; j < 8; ++j) {
            w1x[j] = W1[kc1 * 8 + j];
            w1y[j] = W1[HID + kc1 * 8 + j];
            b1v[j] = b1[kc1 * 8 + j];
        }
        #pragma unroll
        for (int it = 0; it < 10; ++it) {
            int node = it * 32 + n0;         // 0..319
            if (node < 304) {
                uint32_t w[4] = {0u, 0u, 0u, 0u};
                if (node < P) {
                    int prev = (node == 0)     ? P - 1 : node - 1;
                    int next = (node == P - 1) ? 0     : node + 1;
                    float2 xp = *(const float2*)&xs[2 * prev];
                    float2 xc = *(const float2*)&xs[2 * node];
                    float2 xn = *(const float2*)&xs[2 * next];
                    float ax = (xp.x + xc.x + xn.x) * (1.f / 3.f);
                    float ay = (xp.y + xc.y + xn.y) * (1.f / 3.f);
                    #pragma unroll
                    for (int jj = 0; jj < 4; ++jj) {
                        float va = ax * w1x[2*jj]   + ay * w1y[2*jj]   + b1v[2*jj];
                        float vb = ax * w1x[2*jj+1] + ay * w1y[2*jj+1] + b1v[2*jj+1];
                        va = va > 0.f ? va : 0.f;
                        vb = vb > 0.f ? vb : 0.f;
                        w[jj] = pkbf2(va, vb);
                    }
                }
                *(uint4*)&buf[(node * 16 + (kc1 ^ (node & 15))) * 8] =
                    uint4{w[0], w[1], w[2], w[3]};
            }
        }
    }
    __syncthreads();

    run_pass<0>(buf, g_wsw,             b2v, pool, tid);   // h1 -> h2 in place
    __syncthreads();
    run_pass<1>(buf, g_wsw + HID * HID, b3v, pool, tid);   // h2 -> pooled sums
    __syncthreads();

    // ---- FC head (tiny; 256 active threads) ----
    if (tid < 256) {
        int f = tid & 127, half = tid >> 7;
        float p = 0.f;
        const float* fw1c = fw1 + f;
        #pragma unroll 4
        for (int k = half * 64; k < half * 64 + 64; ++k)
            p += pool[k] * fw1c[k * 128];
        parts[half * 128 + f] = p;
    }
    __syncthreads();
    if (tid < 128) {
        float o1 = fb1[tid] + (parts[tid] + parts[128 + tid]) * (1.0f / 300.0f);
        s1[tid] = o1 > 0.f ? o1 : 0.f;
    }
    __syncthreads();
    if (tid < 128) {
        int o = tid >> 6, ln = tid & 63;
        float v = s1[ln] * fw2[ln * 2 + o] + s1[ln + 64] * fw2[(ln + 64) * 2 + o];
        #pragma unroll
        for (int off = 1; off <= 32; off <<= 1)
            v += __shfl_xor(v, off, 64);
        if (ln == 0) out[g * 2 + o] = v + fb2[o];
    }
}

extern "C" void kernel_launch(void* const* d_in, const int* in_sizes, int n_in,
                              void* d_out, int out_size, void* d_ws, size_t ws_size,
                              hipStream_t stream) {
    const float* x   = (const float*)d_in[0];
    const float* W1  = (const float*)d_in[3];
    const float* b1  = (const float*)d_in[4];
    const float* W2  = (const float*)d_in[5];
    const float* b2  = (const float*)d_in[6];
    const float* W3  = (const float*)d_in[7];
    const float* b3  = (const float*)d_in[8];
    const float* fw1 = (const float*)d_in[9];
    const float* fb1 = (const float*)d_in[10];
    const float* fw2 = (const float*)d_in[11];
    const float* fb2 = (const float*)d_in[12];
    float* out = (float*)d_out;

    k_prep <<<dim3(16), dim3(256), 0, stream>>>(W2, W3);
    k_graph<<<dim3(NG), dim3(512), 0, stream>>>(x, W1, b1, b2, b3,
                                                fw1, fb1, fw2, fb2, out);
}